// Round 12
// baseline (337.167 us; speedup 1.0000x reference)
//
#include <hip/hip_runtime.h>
#include <float.h>

#define NN 50000
#define EE 800000
#define NBKT 196   // ceil(NN/256) node buckets
#define T1 4096    // edges per tile
#define CAP2 8192  // max edges per bucket fast path (E[count]=4081, sigma~64)

#define NB_CONV 3125               // NN*16/256
#define NB_PREP 385                // ceil((512*128+256*128+128)/256)
#define NB_CNT  196                // ceil(EE/T1)
#define NB_SETUP (NB_CONV + NB_PREP + NB_CNT)
#define NB_GEMM 782                // 391 x 2
#define MEGA_BLOCKS 512            // <= co-resident capacity (4/CU by LDS+VGPR)

typedef __attribute__((ext_vector_type(8))) short bf16x8;
typedef __attribute__((ext_vector_type(4))) float f32x4;
typedef unsigned short u16;
typedef unsigned int u32;
typedef unsigned char u8;

__device__ __forceinline__ u16 f2bf(float f) {
  u32 u = __builtin_bit_cast(u32, f);
  u32 r = (u + 0x7fffu + ((u >> 16) & 1u)) >> 16;
  return (u16)r;
}
__device__ __forceinline__ float bflo(u32 q) { return __builtin_bit_cast(float, q << 16); }
__device__ __forceinline__ float bfhi(u32 q) { return __builtin_bit_cast(float, q & 0xffff0000u); }

__device__ __forceinline__ void gl_lds16(const u16* g, u16* l) {
  __builtin_amdgcn_global_load_lds((const __attribute__((address_space(1))) void*)g,
                                   (__attribute__((address_space(3))) void*)l, 16, 0, 0);
}

// ---------- merged setup: convert_x | prep (WpT,WpqT,bp) | bucketcnt partials | zero barrier ----------
__global__ __launch_bounds__(256) void k_setup(const float* __restrict__ x,
    const float* __restrict__ post_W, const float* __restrict__ post_b,
    const float* __restrict__ lin_W, const float* __restrict__ lin_b,
    const float* __restrict__ pre_W, const int* __restrict__ ei,
    u16* __restrict__ Xcat, u16* __restrict__ WpT, u16* __restrict__ WpqT,
    float* __restrict__ bp, int* __restrict__ bucket_part, int* __restrict__ bar) {
  __shared__ int hist[256];
  const int bid = blockIdx.x;
  const int t = threadIdx.x;
  if (bid == 0 && t < 2) bar[t] = 0;   // reset grid-barrier state every call (replay-safe)
  if (bid < NB_CONV) {
    int tid = bid * 256 + t;
    int row = tid >> 4;
    int col = (tid & 15) << 3;
    const float4 v0 = *(const float4*)(x + (size_t)row * 128 + col);
    const float4 v1 = *(const float4*)(x + (size_t)row * 128 + col + 4);
    u16 tmp[8] = {f2bf(v0.x), f2bf(v0.y), f2bf(v0.z), f2bf(v0.w),
                  f2bf(v1.x), f2bf(v1.y), f2bf(v1.z), f2bf(v1.w)};
    *(bf16x8*)(Xcat + (size_t)row * 512 + col) = *(bf16x8*)tmp;
  } else if (bid < NB_CONV + NB_PREP) {
    int idx = (bid - NB_CONV) * 256 + t;
    if (idx < 512 * 128) {
      int i = idx >> 7, j = idx & 127;
      float s = 0.f;
#pragma unroll 8
      for (int c = 0; c < 128; c++) s += post_W[i * 128 + c] * lin_W[c * 128 + j];
      WpT[j * 512 + i] = f2bf(s);
    } else if (idx < 512 * 128 + 256 * 128) {
      int u = idx - 512 * 128;
      int j = u >> 7, k = u & 127;
      float v = (j < 128) ? pre_W[k * 128 + j] : pre_W[(128 + k) * 128 + (j - 128)];
      WpqT[j * 128 + k] = f2bf(v);
    } else if (idx < 512 * 128 + 256 * 128 + 128) {
      int j = idx - (512 * 128 + 256 * 128);
      float s = lin_b[j];
      for (int c = 0; c < 128; c++) s += post_b[c] * lin_W[c * 128 + j];
      bp[j] = s;
    }
  } else {
    int tile = bid - (NB_CONV + NB_PREP);
    hist[t] = 0;
    __syncthreads();
    const int e0 = tile * T1;
    const int ec = min(T1, EE - e0);
    for (int j = t; j < ec; j += 256) atomicAdd(&hist[ei[EE + e0 + j] >> 8], 1);
    __syncthreads();
    bucket_part[tile * 256 + t] = hist[t];
  }
}

// ---------- grid barrier (monotonic count/release; state zeroed by k_setup each call) ----------
__device__ __forceinline__ void gbar(int* bar, int phase) {
  __syncthreads();
  if (threadIdx.x == 0) {
    __threadfence();
    int old = __hip_atomic_fetch_add(&bar[0], 1, __ATOMIC_ACQ_REL, __HIP_MEMORY_SCOPE_AGENT);
    if (old == phase * MEGA_BLOCKS - 1) {
      __hip_atomic_store(&bar[1], phase, __ATOMIC_RELEASE, __HIP_MEMORY_SCOPE_AGENT);
    } else {
      while (__hip_atomic_load(&bar[1], __ATOMIC_ACQUIRE, __HIP_MEMORY_SCOPE_AGENT) < phase)
        __builtin_amdgcn_s_sleep(2);
    }
    __threadfence();
  }
  __syncthreads();
}

__device__ __forceinline__ bf16x8 ld_frag(const u16* __restrict__ S, int rowbase,
                                          int kk, int lane) {
  int r = rowbase + (lane & 15);
  int chunk = (kk >> 3) + (lane >> 4);
  int sw = chunk ^ (r & 7);
  return *(const bf16x8*)(S + r * 64 + (sw << 3));
}

// ---------- mega: [scan | gemm_pq x782] -> bar -> bucket x196 -> bar -> sort x196 ----------
__global__ __launch_bounds__(256, 4) void k_mega(const int* __restrict__ ei,
    const u16* __restrict__ Xcat, const u16* __restrict__ WpqT,
    u16* __restrict__ Pb, u8* __restrict__ Qf8,
    const int* __restrict__ bucket_part, int* __restrict__ bucket_base,
    int* __restrict__ bucket_cursor, u32* __restrict__ ebuf,
    int* __restrict__ row_ptr, u16* __restrict__ csr_src, int* __restrict__ bar) {
  __shared__ __align__(16) u8 smem[36864];
  const int t = threadIdx.x;
  const int bid = blockIdx.x;
  const int lane = t & 63, wid = t >> 6;

  // ---- phase A: unit 0 = bucket scan; units 1..782 = gemm_pq tiles ----
  for (int u = bid; u < 1 + NB_GEMM; u += MEGA_BLOCKS) {
    __syncthreads();
    if (u == 0) {
      int* sd = (int*)smem;
      int v = 0;
#pragma unroll 28
      for (int b = 0; b < NB_CNT; ++b) v += bucket_part[b * 256 + t];
      sd[t] = v;
      __syncthreads();
      for (int s = 1; s < 256; s <<= 1) {
        int tv = (t >= s) ? sd[t - s] : 0;
        __syncthreads();
        sd[t] += tv;
        __syncthreads();
      }
      int excl = sd[t] - v;
      bucket_base[t] = excl;      // t>=NBKT: v=0 -> bucket_base[NBKT]==EE
      bucket_cursor[t] = excl;
    } else {
      int g = u - 1;
      int bx = g % 391, ny = g / 391;
      u16* As = (u16*)smem;
      u16* Bs = (u16*)(smem + 16384);
      const int wr = wid >> 1, wc = wid & 1;
      const int row0 = bx * 128;
      const int n0 = ny * 128;
      f32x4 acc[4][4] = {};
      for (int k0 = 0; k0 < 128; k0 += 64) {
#pragma unroll
        for (int it = 0; it < 4; ++it) {
          int c = t + it * 256;
          int row = c >> 3, ch = c & 7;
          gl_lds16(Xcat + (size_t)(row0 + row) * 512 + k0 + ((ch ^ (row & 7)) << 3), As + c * 8);
        }
#pragma unroll
        for (int it = 0; it < 4; ++it) {
          int c = t + it * 256;
          int n = c >> 3, ch = c & 7;
          gl_lds16(WpqT + (size_t)(n0 + n) * 128 + k0 + ((ch ^ (n & 7)) << 3), Bs + c * 8);
        }
        __syncthreads();
#pragma unroll
        for (int kk = 0; kk < 64; kk += 32) {
          bf16x8 af[4], bg[4];
#pragma unroll
          for (int m = 0; m < 4; ++m) af[m] = ld_frag(As, wr * 64 + m * 16, kk, lane);
#pragma unroll
          for (int n = 0; n < 4; ++n) bg[n] = ld_frag(Bs, wc * 64 + n * 16, kk, lane);
#pragma unroll
          for (int m = 0; m < 4; ++m)
#pragma unroll
            for (int n = 0; n < 4; ++n)
              acc[m][n] = __builtin_amdgcn_mfma_f32_16x16x32_bf16(af[m], bg[n], acc[m][n], 0, 0, 0);
        }
        __syncthreads();
      }
      if (n0 == 0) {
#pragma unroll
        for (int m = 0; m < 4; ++m) {
          int rb = row0 + wr * 64 + m * 16 + ((lane >> 4) << 2);
#pragma unroll
          for (int n = 0; n < 4; ++n) {
            int col = wc * 64 + n * 16 + (lane & 15);
#pragma unroll
            for (int r = 0; r < 4; ++r) {
              int row = rb + r;
              if (row < NN) Pb[(size_t)row * 128 + col] = f2bf(acc[m][n][r]);
            }
          }
        }
      } else {
#pragma unroll
        for (int m = 0; m < 4; ++m) {
          int rb = row0 + wr * 64 + m * 16 + ((lane >> 4) << 2);
#pragma unroll
          for (int n = 0; n < 4; ++n) {
            int col = wc * 64 + n * 16 + (lane & 15);
#pragma unroll
            for (int r = 0; r < 4; ++r) {
              int row = rb + r;
              float v = acc[m][n][r];
              float vn = __shfl_xor(v, 1);
              u32 pk = (u32)__builtin_amdgcn_cvt_pk_fp8_f32(v, vn, 0, false);
              if (((lane & 1) == 0) && row < NN)
                *(u16*)(Qf8 + (size_t)row * 128 + col) = (u16)(pk & 0xffffu);
            }
          }
        }
      }
    }
  }
  gbar(bar, 1);

  // ---- phase B: bucket scatter, 196 tiles ----
  for (int u = bid; u < NB_CNT; u += MEGA_BLOCKS) {
    __syncthreads();
    u32* tilebuf = (u32*)smem;
    u32* gpos    = (u32*)(smem + 16384);
    int* hist    = (int*)(smem + 32768);
    int* scn     = (int*)(smem + 33792);
    int* runbase = (int*)(smem + 34816);
    int* ctr     = (int*)(smem + 35840);
    const int e0 = u * T1;
    const int ecount = min(T1, EE - e0);
    hist[t] = 0;
    __syncthreads();
    u32 myp[16];
    int myb[16];
#pragma unroll
    for (int k = 0; k < 16; ++k) {
      int idx = t + k * 256;
      myp[k] = 0; myb[k] = 0;
      if (idx < ecount) {
        int e = e0 + idx;
        int s = ei[e], d = ei[EE + e];
        myp[k] = ((u32)d << 16) | (u32)s;
        int b = d >> 8;
        myb[k] = b;
        atomicAdd(&hist[b], 1);
      }
    }
    __syncthreads();
    int v = hist[t];
    scn[t] = v;
    __syncthreads();
    for (int s_ = 1; s_ < 256; s_ <<= 1) {
      int tv = (t >= s_) ? scn[t - s_] : 0;
      __syncthreads();
      scn[t] += tv;
      __syncthreads();
    }
    int excl = scn[t] - v;
    __syncthreads();
    scn[t] = excl;
    ctr[t] = 0;
    if (v > 0) runbase[t] = atomicAdd(&bucket_cursor[t], v);
    __syncthreads();
#pragma unroll
    for (int k = 0; k < 16; ++k) {
      int idx = t + k * 256;
      if (idx < ecount) {
        int b = myb[k];
        int l = atomicAdd(&ctr[b], 1);
        int slot = scn[b] + l;
        tilebuf[slot] = myp[k];
        gpos[slot] = (u32)(runbase[b] + l);
      }
    }
    __syncthreads();
    for (int j = t; j < ecount; j += 256) ebuf[gpos[j]] = tilebuf[j];
  }
  gbar(bar, 2);

  // ---- phase C: per-bucket counting sort -> row_ptr + csr_src ----
  for (int u = bid; u < NBKT; u += MEGA_BLOCKS) {
    __syncthreads();
    u16* sorted = (u16*)smem;
    int* hist   = (int*)(smem + 32768);
    int* scn    = (int*)(smem + 33792);
    int* ctr    = (int*)(smem + 34816);
    const int base = bucket_base[u];
    const int end = bucket_base[u + 1];
    const int count = end - base;
    hist[t] = 0;
    __syncthreads();
    for (int j = t; j < count; j += 256) atomicAdd(&hist[(ebuf[base + j] >> 16) & 255], 1);
    __syncthreads();
    int v = hist[t];
    scn[t] = v;
    __syncthreads();
    for (int s_ = 1; s_ < 256; s_ <<= 1) {
      int tv = (t >= s_) ? scn[t - s_] : 0;
      __syncthreads();
      scn[t] += tv;
      __syncthreads();
    }
    int excl = scn[t] - v;
    __syncthreads();
    scn[t] = excl;
    ctr[t] = 0;
    int node = u * 256 + t;
    if (node < NN) row_ptr[node] = base + excl;
    if (u == NBKT - 1 && t == 0) row_ptr[NN] = EE;
    __syncthreads();
    if (count <= CAP2) {
      for (int j = t; j < count; j += 256) {
        u32 p = ebuf[base + j];
        int ln = (p >> 16) & 255;
        int l = atomicAdd(&ctr[ln], 1);
        sorted[scn[ln] + l] = (u16)(p & 0xffffu);
      }
      __syncthreads();
      for (int j = t; j < count; j += 256) csr_src[base + j] = sorted[j];
    } else {
      for (int j = t; j < count; j += 256) {
        u32 p = ebuf[base + j];
        int ln = (p >> 16) & 255;
        int l = atomicAdd(&ctr[ln], 1);
        csr_src[base + scn[ln] + l] = (u16)(p & 0xffffu);
      }
    }
  }
}

// ---------- GEMM: out[N,128] fp32 = relu(Xcat[N,512] @ WpT^T + bp) (BM=128) ----------
__global__ __launch_bounds__(256) void k_gemm_out(const u16* __restrict__ Xcat,
    const u16* __restrict__ WpT, const float* __restrict__ bp,
    float* __restrict__ out) {
  __shared__ u16 As[128 * 64];
  __shared__ u16 Bs[128 * 64];
  const int t = threadIdx.x;
  const int lane = t & 63, wid = t >> 6;
  const int wr = wid >> 1, wc = wid & 1;
  const int row0 = blockIdx.x * 128;
  f32x4 acc[4][4] = {};
  for (int k0 = 0; k0 < 512; k0 += 64) {
#pragma unroll
    for (int it = 0; it < 4; ++it) {
      int c = t + it * 256;
      int row = c >> 3, ch = c & 7;
      gl_lds16(Xcat + (size_t)(row0 + row) * 512 + k0 + ((ch ^ (row & 7)) << 3), As + c * 8);
    }
#pragma unroll
    for (int it = 0; it < 4; ++it) {
      int c = t + it * 256;
      int n = c >> 3, ch = c & 7;
      gl_lds16(WpT + (size_t)n * 512 + k0 + ((ch ^ (n & 7)) << 3), Bs + c * 8);
    }
    __syncthreads();
#pragma unroll
    for (int kk = 0; kk < 64; kk += 32) {
      bf16x8 af[4], bg[4];
#pragma unroll
      for (int m = 0; m < 4; ++m) af[m] = ld_frag(As, wr * 64 + m * 16, kk, lane);
#pragma unroll
      for (int n = 0; n < 4; ++n) bg[n] = ld_frag(Bs, wc * 64 + n * 16, kk, lane);
#pragma unroll
      for (int m = 0; m < 4; ++m)
#pragma unroll
        for (int n = 0; n < 4; ++n)
          acc[m][n] = __builtin_amdgcn_mfma_f32_16x16x32_bf16(af[m], bg[n], acc[m][n], 0, 0, 0);
    }
    __syncthreads();
  }
#pragma unroll
  for (int m = 0; m < 4; ++m) {
    int rb = row0 + wr * 64 + m * 16 + ((lane >> 4) << 2);
#pragma unroll
    for (int n = 0; n < 4; ++n) {
      int col = wc * 64 + n * 16 + (lane & 15);
      float bias = bp[col];
#pragma unroll
      for (int r = 0; r < 4; ++r) {
        int row = rb + r;
        if (row < NN) out[(size_t)row * 128 + col] = fmaxf(acc[m][n][r] + bias, 0.f);
      }
    }
  }
}

// ---------- aggregation: one wave per node; fp8 Q gather ----------
__global__ __launch_bounds__(256) void k_aggr(const u16* __restrict__ Pb,
    const u8* __restrict__ Qf8, const float* __restrict__ pre_b,
    const int* __restrict__ row_ptr, const u16* __restrict__ csr_src,
    u16* __restrict__ Xcat) {
  int wid = (blockIdx.x * 256 + threadIdx.x) >> 6;
  int lane = threadIdx.x & 63;
  if (wid >= NN) return;
  int r0 = __builtin_amdgcn_readfirstlane(row_ptr[wid]);
  int r1 = __builtin_amdgcn_readfirstlane(row_ptr[wid + 1]);
  int c = lane * 2;
  const u8* Qbase = Qf8 + c;
  float sx = 0.f, sy = 0.f, mxx = -FLT_MAX, mxy = -FLT_MAX;
  int i = r0;
  for (; i + 16 <= r1; i += 16) {
    int s[16];
#pragma unroll
    for (int k = 0; k < 16; ++k) s[k] = __builtin_amdgcn_readfirstlane((int)csr_src[i + k]);
    u32 q[16];
#pragma unroll
    for (int k = 0; k < 16; ++k) q[k] = (u32)*(const u16*)(Qbase + (size_t)s[k] * 128);
#pragma unroll
    for (int k = 0; k < 16; ++k) {
      float qx = __builtin_amdgcn_cvt_f32_fp8(q[k], 0);
      float qy = __builtin_amdgcn_cvt_f32_fp8(q[k], 1);
      sx += qx; sy += qy;
      mxx = fmaxf(mxx, qx); mxy = fmaxf(mxy, qy);
    }
  }
  if (i + 8 <= r1) {
    int s[8];
#pragma unroll
    for (int k = 0; k < 8; ++k) s[k] = __builtin_amdgcn_readfirstlane((int)csr_src[i + k]);
    u32 q[8];
#pragma unroll
    for (int k = 0; k < 8; ++k) q[k] = (u32)*(const u16*)(Qbase + (size_t)s[k] * 128);
#pragma unroll
    for (int k = 0; k < 8; ++k) {
      float qx = __builtin_amdgcn_cvt_f32_fp8(q[k], 0);
      float qy = __builtin_amdgcn_cvt_f32_fp8(q[k], 1);
      sx += qx; sy += qy;
      mxx = fmaxf(mxx, qx); mxy = fmaxf(mxy, qy);
    }
    i += 8;
  }
  if (i + 4 <= r1) {
    int s[4];
#pragma unroll
    for (int k = 0; k < 4; ++k) s[k] = __builtin_amdgcn_readfirstlane((int)csr_src[i + k]);
    u32 q[4];
#pragma unroll
    for (int k = 0; k < 4; ++k) q[k] = (u32)*(const u16*)(Qbase + (size_t)s[k] * 128);
#pragma unroll
    for (int k = 0; k < 4; ++k) {
      float qx = __builtin_amdgcn_cvt_f32_fp8(q[k], 0);
      float qy = __builtin_amdgcn_cvt_f32_fp8(q[k], 1);
      sx += qx; sy += qy;
      mxx = fmaxf(mxx, qx); mxy = fmaxf(mxy, qy);
    }
    i += 4;
  }
  for (; i < r1; ++i) {
    int s = __builtin_amdgcn_readfirstlane((int)csr_src[i]);
    u32 q = (u32)*(const u16*)(Qbase + (size_t)s * 128);
    float qx = __builtin_amdgcn_cvt_f32_fp8(q, 0);
    float qy = __builtin_amdgcn_cvt_f32_fp8(q, 1);
    sx += qx; sy += qy;
    mxx = fmaxf(mxx, qx); mxy = fmaxf(mxy, qy);
  }
  u32 pu = *(const u32*)(Pb + (size_t)wid * 128 + c);
  float2 b = *(const float2*)(pre_b + c);
  float px = bflo(pu) + b.x;
  float py = bfhi(pu) + b.y;
  int deg = r1 - r0;
  float vm_x = 0.f, vm_y = 0.f, vx_x = 0.f, vx_y = 0.f, vs_x = 0.f, vs_y = 0.f;
  if (deg > 0) {
    float inv = 1.0f / (float)deg;
    vm_x = px + sx * inv;          vm_y = py + sy * inv;
    vx_x = px + mxx;               vx_y = py + mxy;
    vs_x = (float)deg * px + sx;   vs_y = (float)deg * py + sy;
  }
  u16* arow = Xcat + (size_t)wid * 512 + 128;
  *(u32*)(arow + c)       = (u32)f2bf(vm_x) | ((u32)f2bf(vm_y) << 16);
  *(u32*)(arow + 128 + c) = (u32)f2bf(vx_x) | ((u32)f2bf(vx_y) << 16);
  *(u32*)(arow + 256 + c) = (u32)f2bf(vs_x) | ((u32)f2bf(vs_y) << 16);
}

extern "C" void kernel_launch(void* const* d_in, const int* in_sizes, int n_in,
                              void* d_out, int out_size, void* d_ws, size_t ws_size,
                              hipStream_t stream) {
  const float* x      = (const float*)d_in[0];
  const int*   ei     = (const int*)d_in[1];   // [0..E)=src, [E..2E)=dst
  const float* pre_W  = (const float*)d_in[2];
  const float* pre_b  = (const float*)d_in[3];
  const float* post_W = (const float*)d_in[4];
  const float* post_b = (const float*)d_in[5];
  const float* lin_W  = (const float*)d_in[6];
  const float* lin_b  = (const float*)d_in[7];
  float* out = (float*)d_out;

  char* ws = (char*)d_ws;
  size_t off = 0;
  auto alloc = [&](size_t bytes) { size_t o = off; off = (off + bytes + 511) & ~(size_t)511; return o; };
  u16*   Xcat    = (u16*)(ws + alloc((size_t)NN * 512 * 2));
  u16*   Pb      = (u16*)(ws + alloc((size_t)NN * 128 * 2));
  u8*    Qf8     = (u8*)(ws + alloc((size_t)NN * 128));
  u16*   WpT     = (u16*)(ws + alloc(128 * 512 * 2));
  u16*   WpqT    = (u16*)(ws + alloc(256 * 128 * 2));
  float* bp      = (float*)(ws + alloc(128 * 4));
  int*   row_ptr = (int*)(ws + alloc((size_t)(NN + 1) * 4));
  int*   bucket_part   = (int*)(ws + alloc((size_t)NB_CNT * 256 * 4));
  int*   bucket_base   = (int*)(ws + alloc(257 * 4));
  int*   bucket_cursor = (int*)(ws + alloc(256 * 4));
  int*   bar     = (int*)(ws + alloc(2 * 4));
  u32*   ebuf    = (u32*)(ws + alloc((size_t)EE * 4));
  u16*   csr_src = (u16*)(ws + alloc((size_t)EE * 2));
  (void)ws_size; (void)in_sizes; (void)n_in; (void)out_size;

  const int NB_M = (NN + 127) / 128;       // 391

  k_setup<<<NB_SETUP, 256, 0, stream>>>(x, post_W, post_b, lin_W, lin_b, pre_W, ei,
                                        Xcat, WpT, WpqT, bp, bucket_part, bar);
  k_mega<<<MEGA_BLOCKS, 256, 0, stream>>>(ei, Xcat, WpqT, Pb, Qf8, bucket_part,
                                          bucket_base, bucket_cursor, ebuf,
                                          row_ptr, csr_src, bar);
  k_aggr<<<(NN * 64 + 255) / 256, 256, 0, stream>>>(Pb, Qf8, pre_b, row_ptr, csr_src, Xcat);
  k_gemm_out<<<NB_M, 256, 0, stream>>>(Xcat, WpT, bp, out);
}

// Round 13
// 124.636 us; speedup vs baseline: 2.7052x; 2.7052x over previous
//
#include <hip/hip_runtime.h>
#include <float.h>

#define NN 50000
#define EE 800000
#define NBKT 196   // ceil(NN/256) node buckets
#define T1 4096    // edges per tile
#define CAP2 8192  // max edges per bucket fast path (E[count]=4081, sigma~64)

#define NB_CONV 3125               // NN*16/256
#define NB_PREP 385                // ceil((512*128+256*128+128)/256)
#define NB_CNT  196                // ceil(EE/T1)
#define NB_SETUP (NB_CONV + NB_PREP + NB_CNT)

typedef __attribute__((ext_vector_type(8))) short bf16x8;
typedef __attribute__((ext_vector_type(4))) float f32x4;
typedef unsigned short u16;
typedef unsigned int u32;
typedef unsigned char u8;

__device__ __forceinline__ u16 f2bf(float f) {
  u32 u = __builtin_bit_cast(u32, f);
  u32 r = (u + 0x7fffu + ((u >> 16) & 1u)) >> 16;
  return (u16)r;
}
__device__ __forceinline__ float bflo(u32 q) { return __builtin_bit_cast(float, q << 16); }
__device__ __forceinline__ float bfhi(u32 q) { return __builtin_bit_cast(float, q & 0xffff0000u); }

// async global->LDS, 16B per lane; LDS dest must be uniform_base + lane*16 (it is)
__device__ __forceinline__ void gl_lds16(const u16* g, u16* l) {
  __builtin_amdgcn_global_load_lds((const __attribute__((address_space(1))) void*)g,
                                   (__attribute__((address_space(3))) void*)l, 16, 0, 0);
}

// ---------- merged setup: convert_x | prep (WpT,WpqT,bp) | bucketcnt partials ----------
__global__ __launch_bounds__(256) void k_setup(const float* __restrict__ x,
    const float* __restrict__ post_W, const float* __restrict__ post_b,
    const float* __restrict__ lin_W, const float* __restrict__ lin_b,
    const float* __restrict__ pre_W, const int* __restrict__ ei,
    u16* __restrict__ Xcat, u16* __restrict__ WpT, u16* __restrict__ WpqT,
    float* __restrict__ bp, int* __restrict__ bucket_part) {
  __shared__ int hist[256];
  const int bid = blockIdx.x;
  const int t = threadIdx.x;
  if (bid < NB_CONV) {
    int tid = bid * 256 + t;
    int row = tid >> 4;
    int col = (tid & 15) << 3;
    const float4 v0 = *(const float4*)(x + (size_t)row * 128 + col);
    const float4 v1 = *(const float4*)(x + (size_t)row * 128 + col + 4);
    u16 tmp[8] = {f2bf(v0.x), f2bf(v0.y), f2bf(v0.z), f2bf(v0.w),
                  f2bf(v1.x), f2bf(v1.y), f2bf(v1.z), f2bf(v1.w)};
    *(bf16x8*)(Xcat + (size_t)row * 512 + col) = *(bf16x8*)tmp;
  } else if (bid < NB_CONV + NB_PREP) {
    int idx = (bid - NB_CONV) * 256 + t;
    if (idx < 512 * 128) {
      int i = idx >> 7, j = idx & 127;
      float s = 0.f;
#pragma unroll 8
      for (int c = 0; c < 128; c++) s += post_W[i * 128 + c] * lin_W[c * 128 + j];
      WpT[j * 512 + i] = f2bf(s);
    } else if (idx < 512 * 128 + 256 * 128) {
      int u = idx - 512 * 128;
      int j = u >> 7, k = u & 127;
      float v = (j < 128) ? pre_W[k * 128 + j] : pre_W[(128 + k) * 128 + (j - 128)];
      WpqT[j * 128 + k] = f2bf(v);
    } else if (idx < 512 * 128 + 256 * 128 + 128) {
      int j = idx - (512 * 128 + 256 * 128);
      float s = lin_b[j];
      for (int c = 0; c < 128; c++) s += post_b[c] * lin_W[c * 128 + j];
      bp[j] = s;
    }
  } else {
    int tile = bid - (NB_CONV + NB_PREP);
    hist[t] = 0;
    __syncthreads();
    const int e0 = tile * T1;
    const int ec = min(T1, EE - e0);
    for (int j = t; j < ec; j += 256) atomicAdd(&hist[ei[EE + e0 + j] >> 8], 1);
    __syncthreads();
    bucket_part[tile * 256 + t] = hist[t];  // atomic-free partials (no pre-zero needed)
  }
}

// ---------- reduce partials + scan -> bucket_base / bucket_cursor ----------
__global__ void k_scanbucket(const int* __restrict__ bucket_part,
                             int* __restrict__ bucket_base,
                             int* __restrict__ bucket_cursor) {
  __shared__ int sd[256];
  int t = threadIdx.x;  // single block of 256
  int v = 0;
#pragma unroll 4
  for (int b = 0; b < NB_CNT; ++b) v += bucket_part[b * 256 + t];
  sd[t] = v;
  __syncthreads();
  for (int s = 1; s < 256; s <<= 1) {
    int tv = (t >= s) ? sd[t - s] : 0;
    __syncthreads();
    sd[t] += tv;
    __syncthreads();
  }
  int excl = sd[t] - v;
  bucket_base[t] = excl;      // t>=NBKT has v=0 -> bucket_base[NBKT]==EE
  bucket_cursor[t] = excl;
}

// ---------- pass 1: tile-sorted bucket scatter of packed (dst<<16|src) into ebuf ----------
__global__ __launch_bounds__(256) void k_bucket(const int* __restrict__ ei,
    int* __restrict__ bucket_cursor, u32* __restrict__ ebuf) {
  __shared__ u32 tilebuf[T1];
  __shared__ u32 gpos[T1];
  __shared__ int hist[256], scan_[256], runbase[256], ctr[256];
  const int t = threadIdx.x;
  const int e0 = blockIdx.x * T1;
  const int ecount = min(T1, EE - e0);
  hist[t] = 0;
  __syncthreads();
  u32 myp[16];
  int myb[16];
#pragma unroll
  for (int k = 0; k < 16; ++k) {
    int idx = t + k * 256;
    myp[k] = 0; myb[k] = 0;
    if (idx < ecount) {
      int e = e0 + idx;
      int s = ei[e], d = ei[EE + e];
      myp[k] = ((u32)d << 16) | (u32)s;
      int b = d >> 8;
      myb[k] = b;
      atomicAdd(&hist[b], 1);
    }
  }
  __syncthreads();
  int v = hist[t];
  scan_[t] = v;
  __syncthreads();
  for (int s_ = 1; s_ < 256; s_ <<= 1) {
    int tv = (t >= s_) ? scan_[t - s_] : 0;
    __syncthreads();
    scan_[t] += tv;
    __syncthreads();
  }
  int excl = scan_[t] - v;
  __syncthreads();
  scan_[t] = excl;
  ctr[t] = 0;
  if (v > 0) runbase[t] = atomicAdd(&bucket_cursor[t], v);
  __syncthreads();
#pragma unroll
  for (int k = 0; k < 16; ++k) {
    int idx = t + k * 256;
    if (idx < ecount) {
      int b = myb[k];
      int l = atomicAdd(&ctr[b], 1);
      int slot = scan_[b] + l;
      tilebuf[slot] = myp[k];
      gpos[slot] = (u32)(runbase[b] + l);
    }
  }
  __syncthreads();
  for (int j = t; j < ecount; j += 256) ebuf[gpos[j]] = tilebuf[j];
}

// ---------- pass 2: per-bucket LDS counting sort -> row_ptr + per-node CSR (u16 src) ----------
__global__ __launch_bounds__(256) void k_sortbucket(const u32* __restrict__ ebuf,
    const int* __restrict__ bucket_base, int* __restrict__ row_ptr,
    u16* __restrict__ csr_src) {
  __shared__ u16 sorted[CAP2];  // 16 KB
  __shared__ int hist[256], scan_[256], ctr[256];
  const int b = blockIdx.x;
  const int t = threadIdx.x;
  const int base = bucket_base[b];
  const int end = bucket_base[b + 1];
  const int count = end - base;
  hist[t] = 0;
  __syncthreads();
  for (int j = t; j < count; j += 256) atomicAdd(&hist[(ebuf[base + j] >> 16) & 255], 1);
  __syncthreads();
  int v = hist[t];
  scan_[t] = v;
  __syncthreads();
  for (int s_ = 1; s_ < 256; s_ <<= 1) {
    int tv = (t >= s_) ? scan_[t - s_] : 0;
    __syncthreads();
    scan_[t] += tv;
    __syncthreads();
  }
  int excl = scan_[t] - v;
  __syncthreads();
  scan_[t] = excl;
  ctr[t] = 0;
  int node = b * 256 + t;
  if (node < NN) row_ptr[node] = base + excl;
  if (b == NBKT - 1 && t == 0) row_ptr[NN] = EE;
  __syncthreads();
  if (count <= CAP2) {
    for (int j = t; j < count; j += 256) {
      u32 p = ebuf[base + j];
      int ln = (p >> 16) & 255;
      int l = atomicAdd(&ctr[ln], 1);
      sorted[scan_[ln] + l] = (u16)(p & 0xffffu);
    }
    __syncthreads();
    for (int j = t; j < count; j += 256) csr_src[base + j] = sorted[j];
  } else {
    for (int j = t; j < count; j += 256) {
      u32 p = ebuf[base + j];
      int ln = (p >> 16) & 255;
      int l = atomicAdd(&ctr[ln], 1);
      csr_src[base + scan_[ln] + l] = (u16)(p & 0xffffu);
    }
  }
}

// ---------- MFMA GEMM staging via global_load_lds (pre-swizzled source, linear LDS dest) ----------
template <int KTOT, int LDA>
__device__ __forceinline__ void stage_tiles(const u16* __restrict__ A,
    const u16* __restrict__ BT, int row0, int n0, int k0,
    u16* __restrict__ As, u16* __restrict__ Bs, int t) {
#pragma unroll
  for (int it = 0; it < 4; ++it) {
    int c = t + it * 256;
    int row = c >> 3, ch = c & 7;
    gl_lds16(A + (size_t)(row0 + row) * LDA + k0 + ((ch ^ (row & 7)) << 3), As + c * 8);
  }
#pragma unroll
  for (int it = 0; it < 4; ++it) {
    int c = t + it * 256;
    int n = c >> 3, ch = c & 7;
    gl_lds16(BT + (size_t)(n0 + n) * KTOT + k0 + ((ch ^ (n & 7)) << 3), Bs + c * 8);
  }
}

__device__ __forceinline__ bf16x8 ld_frag(const u16* __restrict__ S, int rowbase,
                                          int kk, int lane) {
  int r = rowbase + (lane & 15);
  int chunk = (kk >> 3) + (lane >> 4);
  int sw = chunk ^ (r & 7);
  return *(const bf16x8*)(S + r * 64 + (sw << 3));
}

// ---------- GEMM: P[N,128] bf16 (y=0) / Q[N,128] fp8 (y=1) = Xcat[:,0:128] @ WpqT^T ----------
__global__ __launch_bounds__(256) void k_gemm_pq(const u16* __restrict__ Xcat,
    const u16* __restrict__ WpqT, u16* __restrict__ Pb, u8* __restrict__ Qf8) {
  __shared__ u16 As[128 * 64];
  __shared__ u16 Bs[128 * 64];
  const int t = threadIdx.x;
  const int lane = t & 63, wid = t >> 6;
  const int wr = wid >> 1, wc = wid & 1;
  const int row0 = blockIdx.x * 128;
  const int n0 = blockIdx.y * 128;
  f32x4 acc[4][4] = {};
  for (int k0 = 0; k0 < 128; k0 += 64) {
    stage_tiles<128, 512>(Xcat, WpqT, row0, n0, k0, As, Bs, t);
    __syncthreads();
#pragma unroll
    for (int kk = 0; kk < 64; kk += 32) {
      bf16x8 af[4], bg[4];
#pragma unroll
      for (int m = 0; m < 4; ++m) af[m] = ld_frag(As, wr * 64 + m * 16, kk, lane);
#pragma unroll
      for (int n = 0; n < 4; ++n) bg[n] = ld_frag(Bs, wc * 64 + n * 16, kk, lane);
#pragma unroll
      for (int m = 0; m < 4; ++m)
#pragma unroll
        for (int n = 0; n < 4; ++n)
          acc[m][n] = __builtin_amdgcn_mfma_f32_16x16x32_bf16(af[m], bg[n], acc[m][n], 0, 0, 0);
    }
    __syncthreads();
  }
  if (n0 == 0) {
#pragma unroll
    for (int m = 0; m < 4; ++m) {
      int rb = row0 + wr * 64 + m * 16 + ((lane >> 4) << 2);
#pragma unroll
      for (int n = 0; n < 4; ++n) {
        int col = wc * 64 + n * 16 + (lane & 15);
#pragma unroll
        for (int r = 0; r < 4; ++r) {
          int row = rb + r;
          if (row < NN) Pb[(size_t)row * 128 + col] = f2bf(acc[m][n][r]);
        }
      }
    }
  } else {
    // fp8 epilogue: HW pack (cvt_pk_fp8_f32, RNE, OCP) + paired u16 stores from even lanes
#pragma unroll
    for (int m = 0; m < 4; ++m) {
      int rb = row0 + wr * 64 + m * 16 + ((lane >> 4) << 2);
#pragma unroll
      for (int n = 0; n < 4; ++n) {
        int col = wc * 64 + n * 16 + (lane & 15);
#pragma unroll
        for (int r = 0; r < 4; ++r) {
          int row = rb + r;
          float v = acc[m][n][r];
          float vn = __shfl_xor(v, 1);
          u32 pk = (u32)__builtin_amdgcn_cvt_pk_fp8_f32(v, vn, 0, false);
          if (((lane & 1) == 0) && row < NN)
            *(u16*)(Qf8 + (size_t)row * 128 + col) = (u16)(pk & 0xffffu);
        }
      }
    }
  }
}

// ---------- GEMM: out[N,128] fp32 = relu(Xcat[N,512] @ WpT^T + bp) (BM=128) ----------
__global__ __launch_bounds__(256) void k_gemm_out(const u16* __restrict__ Xcat,
    const u16* __restrict__ WpT, const float* __restrict__ bp,
    float* __restrict__ out) {
  __shared__ u16 As[128 * 64];
  __shared__ u16 Bs[128 * 64];
  const int t = threadIdx.x;
  const int lane = t & 63, wid = t >> 6;
  const int wr = wid >> 1, wc = wid & 1;
  const int row0 = blockIdx.x * 128;
  f32x4 acc[4][4] = {};
  for (int k0 = 0; k0 < 512; k0 += 64) {
    stage_tiles<512, 512>(Xcat, WpT, row0, 0, k0, As, Bs, t);
    __syncthreads();
#pragma unroll
    for (int kk = 0; kk < 64; kk += 32) {
      bf16x8 af[4], bg[4];
#pragma unroll
      for (int m = 0; m < 4; ++m) af[m] = ld_frag(As, wr * 64 + m * 16, kk, lane);
#pragma unroll
      for (int n = 0; n < 4; ++n) bg[n] = ld_frag(Bs, wc * 64 + n * 16, kk, lane);
#pragma unroll
      for (int m = 0; m < 4; ++m)
#pragma unroll
        for (int n = 0; n < 4; ++n)
          acc[m][n] = __builtin_amdgcn_mfma_f32_16x16x32_bf16(af[m], bg[n], acc[m][n], 0, 0, 0);
    }
    __syncthreads();
  }
#pragma unroll
  for (int m = 0; m < 4; ++m) {
    int rb = row0 + wr * 64 + m * 16 + ((lane >> 4) << 2);
#pragma unroll
    for (int n = 0; n < 4; ++n) {
      int col = wc * 64 + n * 16 + (lane & 15);
      float bias = bp[col];
#pragma unroll
      for (int r = 0; r < 4; ++r) {
        int row = rb + r;
        if (row < NN) out[(size_t)row * 128 + col] = fmaxf(acc[m][n][r] + bias, 0.f);
      }
    }
  }
}

// ---------- aggregation: one wave per node; fp8 Q gather (halved bytes) ----------
__global__ __launch_bounds__(256) void k_aggr(const u16* __restrict__ Pb,
    const u8* __restrict__ Qf8, const float* __restrict__ pre_b,
    const int* __restrict__ row_ptr, const u16* __restrict__ csr_src,
    u16* __restrict__ Xcat) {
  int wid = (blockIdx.x * 256 + threadIdx.x) >> 6;
  int lane = threadIdx.x & 63;
  if (wid >= NN) return;
  int r0 = __builtin_amdgcn_readfirstlane(row_ptr[wid]);
  int r1 = __builtin_amdgcn_readfirstlane(row_ptr[wid + 1]);
  int c = lane * 2;
  const u8* Qbase = Qf8 + c;  // row s -> Qbase + s*128 (2 fp8 bytes per lane)
  float sx = 0.f, sy = 0.f, mxx = -FLT_MAX, mxy = -FLT_MAX;
  int i = r0;
  for (; i + 16 <= r1; i += 16) {
    int s[16];
#pragma unroll
    for (int k = 0; k < 16; ++k) s[k] = __builtin_amdgcn_readfirstlane((int)csr_src[i + k]);
    u32 q[16];
#pragma unroll
    for (int k = 0; k < 16; ++k) q[k] = (u32)*(const u16*)(Qbase + (size_t)s[k] * 128);
#pragma unroll
    for (int k = 0; k < 16; ++k) {
      float qx = __builtin_amdgcn_cvt_f32_fp8(q[k], 0);
      float qy = __builtin_amdgcn_cvt_f32_fp8(q[k], 1);
      sx += qx; sy += qy;
      mxx = fmaxf(mxx, qx); mxy = fmaxf(mxy, qy);
    }
  }
  if (i + 8 <= r1) {
    int s[8];
#pragma unroll
    for (int k = 0; k < 8; ++k) s[k] = __builtin_amdgcn_readfirstlane((int)csr_src[i + k]);
    u32 q[8];
#pragma unroll
    for (int k = 0; k < 8; ++k) q[k] = (u32)*(const u16*)(Qbase + (size_t)s[k] * 128);
#pragma unroll
    for (int k = 0; k < 8; ++k) {
      float qx = __builtin_amdgcn_cvt_f32_fp8(q[k], 0);
      float qy = __builtin_amdgcn_cvt_f32_fp8(q[k], 1);
      sx += qx; sy += qy;
      mxx = fmaxf(mxx, qx); mxy = fmaxf(mxy, qy);
    }
    i += 8;
  }
  if (i + 4 <= r1) {
    int s[4];
#pragma unroll
    for (int k = 0; k < 4; ++k) s[k] = __builtin_amdgcn_readfirstlane((int)csr_src[i + k]);
    u32 q[4];
#pragma unroll
    for (int k = 0; k < 4; ++k) q[k] = (u32)*(const u16*)(Qbase + (size_t)s[k] * 128);
#pragma unroll
    for (int k = 0; k < 4; ++k) {
      float qx = __builtin_amdgcn_cvt_f32_fp8(q[k], 0);
      float qy = __builtin_amdgcn_cvt_f32_fp8(q[k], 1);
      sx += qx; sy += qy;
      mxx = fmaxf(mxx, qx); mxy = fmaxf(mxy, qy);
    }
    i += 4;
  }
  for (; i < r1; ++i) {
    int s = __builtin_amdgcn_readfirstlane((int)csr_src[i]);
    u32 q = (u32)*(const u16*)(Qbase + (size_t)s * 128);
    float qx = __builtin_amdgcn_cvt_f32_fp8(q, 0);
    float qy = __builtin_amdgcn_cvt_f32_fp8(q, 1);
    sx += qx; sy += qy;
    mxx = fmaxf(mxx, qx); mxy = fmaxf(mxy, qy);
  }
  u32 pu = *(const u32*)(Pb + (size_t)wid * 128 + c);
  float2 b = *(const float2*)(pre_b + c);
  float px = bflo(pu) + b.x;
  float py = bfhi(pu) + b.y;
  int deg = r1 - r0;
  float vm_x = 0.f, vm_y = 0.f, vx_x = 0.f, vx_y = 0.f, vs_x = 0.f, vs_y = 0.f;
  if (deg > 0) {
    float inv = 1.0f / (float)deg;
    vm_x = px + sx * inv;          vm_y = py + sy * inv;
    vx_x = px + mxx;               vx_y = py + mxy;
    vs_x = (float)deg * px + sx;   vs_y = (float)deg * py + sy;
  }
  u16* arow = Xcat + (size_t)wid * 512 + 128;
  *(u32*)(arow + c)       = (u32)f2bf(vm_x) | ((u32)f2bf(vm_y) << 16);
  *(u32*)(arow + 128 + c) = (u32)f2bf(vx_x) | ((u32)f2bf(vx_y) << 16);
  *(u32*)(arow + 256 + c) = (u32)f2bf(vs_x) | ((u32)f2bf(vs_y) << 16);
}

extern "C" void kernel_launch(void* const* d_in, const int* in_sizes, int n_in,
                              void* d_out, int out_size, void* d_ws, size_t ws_size,
                              hipStream_t stream) {
  const float* x      = (const float*)d_in[0];
  const int*   ei     = (const int*)d_in[1];   // [0..E)=src, [E..2E)=dst
  const float* pre_W  = (const float*)d_in[2];
  const float* pre_b  = (const float*)d_in[3];
  const float* post_W = (const float*)d_in[4];
  const float* post_b = (const float*)d_in[5];
  const float* lin_W  = (const float*)d_in[6];
  const float* lin_b  = (const float*)d_in[7];
  float* out = (float*)d_out;

  char* ws = (char*)d_ws;
  size_t off = 0;
  auto alloc = [&](size_t bytes) { size_t o = off; off = (off + bytes + 511) & ~(size_t)511; return o; };
  u16*   Xcat    = (u16*)(ws + alloc((size_t)NN * 512 * 2));
  u16*   Pb      = (u16*)(ws + alloc((size_t)NN * 128 * 2));
  u8*    Qf8     = (u8*)(ws + alloc((size_t)NN * 128));
  u16*   WpT     = (u16*)(ws + alloc(128 * 512 * 2));
  u16*   WpqT    = (u16*)(ws + alloc(256 * 128 * 2));
  float* bp      = (float*)(ws + alloc(128 * 4));
  int*   row_ptr = (int*)(ws + alloc((size_t)(NN + 1) * 4));
  int*   bucket_part   = (int*)(ws + alloc((size_t)NB_CNT * 256 * 4));
  int*   bucket_base   = (int*)(ws + alloc(257 * 4));
  int*   bucket_cursor = (int*)(ws + alloc(256 * 4));
  u32*   ebuf    = (u32*)(ws + alloc((size_t)EE * 4));
  u16*   csr_src = (u16*)(ws + alloc((size_t)EE * 2));
  (void)ws_size; (void)in_sizes; (void)n_in; (void)out_size;

  const int NB_M = (NN + 127) / 128;       // 391

  k_setup<<<NB_SETUP, 256, 0, stream>>>(x, post_W, post_b, lin_W, lin_b, pre_W, ei,
                                        Xcat, WpT, WpqT, bp, bucket_part);
  k_scanbucket<<<1, 256, 0, stream>>>(bucket_part, bucket_base, bucket_cursor);
  k_bucket<<<NB_CNT, 256, 0, stream>>>(ei, bucket_cursor, ebuf);
  k_sortbucket<<<NBKT, 256, 0, stream>>>(ebuf, bucket_base, row_ptr, csr_src);
  k_gemm_pq<<<dim3(NB_M, 2), 256, 0, stream>>>(Xcat, WpqT, Pb, Qf8);
  k_aggr<<<(NN * 64 + 255) / 256, 256, 0, stream>>>(Pb, Qf8, pre_b, row_ptr, csr_src, Xcat);
  k_gemm_out<<<NB_M, 256, 0, stream>>>(Xcat, WpT, bp, out);
}

// Round 14
// 121.827 us; speedup vs baseline: 2.7676x; 1.0231x over previous
//
#include <hip/hip_runtime.h>
#include <float.h>

#define NN 50000
#define EE 800000
#define NBKT 196   // ceil(NN/256) node buckets
#define T1 4096    // edges per tile
#define CAP2 8192  // max edges per bucket fast path (E[count]=4081, sigma~64)

#define NB_PREP 385                // ceil((512*128+256*128+128)/256)
#define NB_CNT  196                // ceil(EE/T1)
#define NB_SETUP (NB_PREP + NB_CNT)

typedef __attribute__((ext_vector_type(8))) short bf16x8;
typedef __attribute__((ext_vector_type(4))) float f32x4;
typedef unsigned short u16;
typedef unsigned int u32;
typedef unsigned char u8;

__device__ __forceinline__ u16 f2bf(float f) {
  u32 u = __builtin_bit_cast(u32, f);
  u32 r = (u + 0x7fffu + ((u >> 16) & 1u)) >> 16;
  return (u16)r;
}
__device__ __forceinline__ float bflo(u32 q) { return __builtin_bit_cast(float, q << 16); }
__device__ __forceinline__ float bfhi(u32 q) { return __builtin_bit_cast(float, q & 0xffff0000u); }

// async global->LDS, 16B per lane; LDS dest must be uniform_base + lane*16 (it is)
__device__ __forceinline__ void gl_lds16(const u16* g, u16* l) {
  __builtin_amdgcn_global_load_lds((const __attribute__((address_space(1))) void*)g,
                                   (__attribute__((address_space(3))) void*)l, 16, 0, 0);
}

// ---------- setup: prep (WpT,WpqT,bp) | bucketcnt partials ----------
__global__ __launch_bounds__(256) void k_setup(const float* __restrict__ post_W,
    const float* __restrict__ post_b, const float* __restrict__ lin_W,
    const float* __restrict__ lin_b, const float* __restrict__ pre_W,
    const int* __restrict__ ei, u16* __restrict__ WpT, u16* __restrict__ WpqT,
    float* __restrict__ bp, int* __restrict__ bucket_part) {
  __shared__ int hist[256];
  const int bid = blockIdx.x;
  const int t = threadIdx.x;
  if (bid < NB_PREP) {
    int idx = bid * 256 + t;
    if (idx < 512 * 128) {
      int i = idx >> 7, j = idx & 127;
      float s = 0.f;
#pragma unroll 8
      for (int c = 0; c < 128; c++) s += post_W[i * 128 + c] * lin_W[c * 128 + j];
      WpT[j * 512 + i] = f2bf(s);
    } else if (idx < 512 * 128 + 256 * 128) {
      int u = idx - 512 * 128;
      int j = u >> 7, k = u & 127;
      float v = (j < 128) ? pre_W[k * 128 + j] : pre_W[(128 + k) * 128 + (j - 128)];
      WpqT[j * 128 + k] = f2bf(v);
    } else if (idx < 512 * 128 + 256 * 128 + 128) {
      int j = idx - (512 * 128 + 256 * 128);
      float s = lin_b[j];
      for (int c = 0; c < 128; c++) s += post_b[c] * lin_W[c * 128 + j];
      bp[j] = s;
    }
  } else {
    int tile = bid - NB_PREP;
    hist[t] = 0;
    __syncthreads();
    const int e0 = tile * T1;
    const int ec = min(T1, EE - e0);
    for (int j = t; j < ec; j += 256) atomicAdd(&hist[ei[EE + e0 + j] >> 8], 1);
    __syncthreads();
    bucket_part[tile * 256 + t] = hist[t];  // atomic-free partials (no pre-zero needed)
  }
}

// ---------- reduce partials + scan -> bucket_base / bucket_cursor ----------
__global__ void k_scanbucket(const int* __restrict__ bucket_part,
                             int* __restrict__ bucket_base,
                             int* __restrict__ bucket_cursor) {
  __shared__ int sd[256];
  int t = threadIdx.x;  // single block of 256
  int v = 0;
#pragma unroll 4
  for (int b = 0; b < NB_CNT; ++b) v += bucket_part[b * 256 + t];
  sd[t] = v;
  __syncthreads();
  for (int s = 1; s < 256; s <<= 1) {
    int tv = (t >= s) ? sd[t - s] : 0;
    __syncthreads();
    sd[t] += tv;
    __syncthreads();
  }
  int excl = sd[t] - v;
  bucket_base[t] = excl;      // t>=NBKT has v=0 -> bucket_base[NBKT]==EE
  bucket_cursor[t] = excl;
}

// ---------- pass 1: tile-sorted bucket scatter of packed (dst<<16|src) into ebuf ----------
__global__ __launch_bounds__(256) void k_bucket(const int* __restrict__ ei,
    int* __restrict__ bucket_cursor, u32* __restrict__ ebuf) {
  __shared__ u32 tilebuf[T1];
  __shared__ u32 gpos[T1];
  __shared__ int hist[256], scan_[256], runbase[256], ctr[256];
  const int t = threadIdx.x;
  const int e0 = blockIdx.x * T1;
  const int ecount = min(T1, EE - e0);
  hist[t] = 0;
  __syncthreads();
  u32 myp[16];
  int myb[16];
#pragma unroll
  for (int k = 0; k < 16; ++k) {
    int idx = t + k * 256;
    myp[k] = 0; myb[k] = 0;
    if (idx < ecount) {
      int e = e0 + idx;
      int s = ei[e], d = ei[EE + e];
      myp[k] = ((u32)d << 16) | (u32)s;
      int b = d >> 8;
      myb[k] = b;
      atomicAdd(&hist[b], 1);
    }
  }
  __syncthreads();
  int v = hist[t];
  scan_[t] = v;
  __syncthreads();
  for (int s_ = 1; s_ < 256; s_ <<= 1) {
    int tv = (t >= s_) ? scan_[t - s_] : 0;
    __syncthreads();
    scan_[t] += tv;
    __syncthreads();
  }
  int excl = scan_[t] - v;
  __syncthreads();
  scan_[t] = excl;
  ctr[t] = 0;
  if (v > 0) runbase[t] = atomicAdd(&bucket_cursor[t], v);
  __syncthreads();
#pragma unroll
  for (int k = 0; k < 16; ++k) {
    int idx = t + k * 256;
    if (idx < ecount) {
      int b = myb[k];
      int l = atomicAdd(&ctr[b], 1);
      int slot = scan_[b] + l;
      tilebuf[slot] = myp[k];
      gpos[slot] = (u32)(runbase[b] + l);
    }
  }
  __syncthreads();
  for (int j = t; j < ecount; j += 256) ebuf[gpos[j]] = tilebuf[j];
}

// ---------- pass 2: per-bucket LDS counting sort -> row_ptr + per-node CSR (u16 src) ----------
__global__ __launch_bounds__(256) void k_sortbucket(const u32* __restrict__ ebuf,
    const int* __restrict__ bucket_base, int* __restrict__ row_ptr,
    u16* __restrict__ csr_src) {
  __shared__ u16 sorted[CAP2];  // 16 KB
  __shared__ int hist[256], scan_[256], ctr[256];
  const int b = blockIdx.x;
  const int t = threadIdx.x;
  const int base = bucket_base[b];
  const int end = bucket_base[b + 1];
  const int count = end - base;
  hist[t] = 0;
  __syncthreads();
  for (int j = t; j < count; j += 256) atomicAdd(&hist[(ebuf[base + j] >> 16) & 255], 1);
  __syncthreads();
  int v = hist[t];
  scan_[t] = v;
  __syncthreads();
  for (int s_ = 1; s_ < 256; s_ <<= 1) {
    int tv = (t >= s_) ? scan_[t - s_] : 0;
    __syncthreads();
    scan_[t] += tv;
    __syncthreads();
  }
  int excl = scan_[t] - v;
  __syncthreads();
  scan_[t] = excl;
  ctr[t] = 0;
  int node = b * 256 + t;
  if (node < NN) row_ptr[node] = base + excl;
  if (b == NBKT - 1 && t == 0) row_ptr[NN] = EE;
  __syncthreads();
  if (count <= CAP2) {
    for (int j = t; j < count; j += 256) {
      u32 p = ebuf[base + j];
      int ln = (p >> 16) & 255;
      int l = atomicAdd(&ctr[ln], 1);
      sorted[scan_[ln] + l] = (u16)(p & 0xffffu);
    }
    __syncthreads();
    for (int j = t; j < count; j += 256) csr_src[base + j] = sorted[j];
  } else {
    for (int j = t; j < count; j += 256) {
      u32 p = ebuf[base + j];
      int ln = (p >> 16) & 255;
      int l = atomicAdd(&ctr[ln], 1);
      csr_src[base + scan_[ln] + l] = (u16)(p & 0xffffu);
    }
  }
}

__device__ __forceinline__ bf16x8 ld_frag(const u16* __restrict__ S, int rowbase,
                                          int kk, int lane) {
  int r = rowbase + (lane & 15);
  int chunk = (kk >> 3) + (lane >> 4);
  int sw = chunk ^ (r & 7);
  return *(const bf16x8*)(S + r * 64 + (sw << 3));
}

// ---------- GEMM (single pass, BN=256, 8 waves): P bf16 + Q fp8 = x @ WpqT^T.
// A staged from fp32 x with inline f2bf (identical to old convert_x), ALSO written
// to Xcat[:,0:128] as a side effect (replaces the deleted conversion pass).
__global__ __launch_bounds__(512) void k_gemm_pq(const float* __restrict__ x,
    const u16* __restrict__ WpqT, u16* __restrict__ Xcat,
    u16* __restrict__ Pb, u8* __restrict__ Qf8) {
  __shared__ u16 As[128 * 64];
  __shared__ u16 Bs[256 * 64];
  const int t = threadIdx.x;
  const int lane = t & 63, wid = t >> 6;
  const int wr = wid >> 2, wc = wid & 3;
  const int row0 = blockIdx.x * 128;
  f32x4 acc[4][4] = {};
  for (int k0 = 0; k0 < 128; k0 += 64) {
    // A: reg-stage fp32 -> bf16, swizzled ds_write; side-write Xcat[:,0:128]
#pragma unroll
    for (int it = 0; it < 2; ++it) {
      int c = t + it * 512;           // 1024 chunks of 8 bf16
      int row = c >> 3, ch = c & 7;
      int gr = row0 + row;
      u16 tmp[8] = {};
      if (gr < NN) {
        const float4 v0 = *(const float4*)(x + (size_t)gr * 128 + k0 + (ch << 3));
        const float4 v1 = *(const float4*)(x + (size_t)gr * 128 + k0 + (ch << 3) + 4);
        tmp[0] = f2bf(v0.x); tmp[1] = f2bf(v0.y); tmp[2] = f2bf(v0.z); tmp[3] = f2bf(v0.w);
        tmp[4] = f2bf(v1.x); tmp[5] = f2bf(v1.y); tmp[6] = f2bf(v1.z); tmp[7] = f2bf(v1.w);
        *(bf16x8*)(Xcat + (size_t)gr * 512 + k0 + (ch << 3)) = *(bf16x8*)tmp;
      }
      *(bf16x8*)(As + row * 64 + ((ch ^ (row & 7)) << 3)) = *(bf16x8*)tmp;
    }
    // B: async gload_lds, pre-swizzled source (256 rows x 64 k)
#pragma unroll
    for (int it = 0; it < 4; ++it) {
      int c = t + it * 512;           // 2048 chunks
      int n = c >> 3, ch = c & 7;
      gl_lds16(WpqT + (size_t)n * 128 + k0 + ((ch ^ (n & 7)) << 3), Bs + c * 8);
    }
    __syncthreads();
#pragma unroll
    for (int kk = 0; kk < 64; kk += 32) {
      bf16x8 af[4], bg[4];
#pragma unroll
      for (int m = 0; m < 4; ++m) af[m] = ld_frag(As, wr * 64 + m * 16, kk, lane);
#pragma unroll
      for (int n = 0; n < 4; ++n) bg[n] = ld_frag(Bs, wc * 64 + n * 16, kk, lane);
#pragma unroll
      for (int m = 0; m < 4; ++m)
#pragma unroll
        for (int n = 0; n < 4; ++n)
          acc[m][n] = __builtin_amdgcn_mfma_f32_16x16x32_bf16(af[m], bg[n], acc[m][n], 0, 0, 0);
    }
    __syncthreads();
  }
#pragma unroll
  for (int m = 0; m < 4; ++m) {
    int rb = row0 + wr * 64 + m * 16 + ((lane >> 4) << 2);
#pragma unroll
    for (int n = 0; n < 4; ++n) {
      int col = wc * 64 + n * 16 + (lane & 15);   // 0..255 (wave-uniform half)
      if (col < 128) {
#pragma unroll
        for (int r = 0; r < 4; ++r) {
          int row = rb + r;
          if (row < NN) Pb[(size_t)row * 128 + col] = f2bf(acc[m][n][r]);
        }
      } else {
        int qc = col - 128;
#pragma unroll
        for (int r = 0; r < 4; ++r) {
          int row = rb + r;
          float v = acc[m][n][r];
          float vn = __shfl_xor(v, 1);
          u32 pk = (u32)__builtin_amdgcn_cvt_pk_fp8_f32(v, vn, 0, false);
          if (((lane & 1) == 0) && row < NN)
            *(u16*)(Qf8 + (size_t)row * 128 + qc) = (u16)(pk & 0xffffu);
        }
      }
    }
  }
}

// ---------- GEMM: out[N,128] fp32 = relu(Xcat[N,512] @ WpT^T + bp) (BM=128) ----------
__global__ __launch_bounds__(256) void k_gemm_out(const u16* __restrict__ Xcat,
    const u16* __restrict__ WpT, const float* __restrict__ bp,
    float* __restrict__ out) {
  __shared__ u16 As[128 * 64];
  __shared__ u16 Bs[128 * 64];
  const int t = threadIdx.x;
  const int lane = t & 63, wid = t >> 6;
  const int wr = wid >> 1, wc = wid & 1;
  const int row0 = blockIdx.x * 128;
  f32x4 acc[4][4] = {};
  for (int k0 = 0; k0 < 512; k0 += 64) {
#pragma unroll
    for (int it = 0; it < 4; ++it) {
      int c = t + it * 256;
      int row = c >> 3, ch = c & 7;
      gl_lds16(Xcat + (size_t)(row0 + row) * 512 + k0 + ((ch ^ (row & 7)) << 3), As + c * 8);
    }
#pragma unroll
    for (int it = 0; it < 4; ++it) {
      int c = t + it * 256;
      int n = c >> 3, ch = c & 7;
      gl_lds16(WpT + (size_t)n * 512 + k0 + ((ch ^ (n & 7)) << 3), Bs + c * 8);
    }
    __syncthreads();
#pragma unroll
    for (int kk = 0; kk < 64; kk += 32) {
      bf16x8 af[4], bg[4];
#pragma unroll
      for (int m = 0; m < 4; ++m) af[m] = ld_frag(As, wr * 64 + m * 16, kk, lane);
#pragma unroll
      for (int n = 0; n < 4; ++n) bg[n] = ld_frag(Bs, wc * 64 + n * 16, kk, lane);
#pragma unroll
      for (int m = 0; m < 4; ++m)
#pragma unroll
        for (int n = 0; n < 4; ++n)
          acc[m][n] = __builtin_amdgcn_mfma_f32_16x16x32_bf16(af[m], bg[n], acc[m][n], 0, 0, 0);
    }
    __syncthreads();
  }
#pragma unroll
  for (int m = 0; m < 4; ++m) {
    int rb = row0 + wr * 64 + m * 16 + ((lane >> 4) << 2);
#pragma unroll
    for (int n = 0; n < 4; ++n) {
      int col = wc * 64 + n * 16 + (lane & 15);
      float bias = bp[col];
#pragma unroll
      for (int r = 0; r < 4; ++r) {
        int row = rb + r;
        if (row < NN) out[(size_t)row * 128 + col] = fmaxf(acc[m][n][r] + bias, 0.f);
      }
    }
  }
}

// ---------- aggregation: one wave per node; fp8 Q gather (halved bytes) ----------
__global__ __launch_bounds__(256) void k_aggr(const u16* __restrict__ Pb,
    const u8* __restrict__ Qf8, const float* __restrict__ pre_b,
    const int* __restrict__ row_ptr, const u16* __restrict__ csr_src,
    u16* __restrict__ Xcat) {
  int wid = (blockIdx.x * 256 + threadIdx.x) >> 6;
  int lane = threadIdx.x & 63;
  if (wid >= NN) return;
  int r0 = __builtin_amdgcn_readfirstlane(row_ptr[wid]);
  int r1 = __builtin_amdgcn_readfirstlane(row_ptr[wid + 1]);
  int c = lane * 2;
  const u8* Qbase = Qf8 + c;  // row s -> Qbase + s*128 (2 fp8 bytes per lane)
  float sx = 0.f, sy = 0.f, mxx = -FLT_MAX, mxy = -FLT_MAX;
  int i = r0;
  for (; i + 16 <= r1; i += 16) {
    int s[16];
#pragma unroll
    for (int k = 0; k < 16; ++k) s[k] = __builtin_amdgcn_readfirstlane((int)csr_src[i + k]);
    u32 q[16];
#pragma unroll
    for (int k = 0; k < 16; ++k) q[k] = (u32)*(const u16*)(Qbase + (size_t)s[k] * 128);
#pragma unroll
    for (int k = 0; k < 16; ++k) {
      float qx = __builtin_amdgcn_cvt_f32_fp8(q[k], 0);
      float qy = __builtin_amdgcn_cvt_f32_fp8(q[k], 1);
      sx += qx; sy += qy;
      mxx = fmaxf(mxx, qx); mxy = fmaxf(mxy, qy);
    }
  }
  if (i + 8 <= r1) {
    int s[8];
#pragma unroll
    for (int k = 0; k < 8; ++k) s[k] = __builtin_amdgcn_readfirstlane((int)csr_src[i + k]);
    u32 q[8];
#pragma unroll
    for (int k = 0; k < 8; ++k) q[k] = (u32)*(const u16*)(Qbase + (size_t)s[k] * 128);
#pragma unroll
    for (int k = 0; k < 8; ++k) {
      float qx = __builtin_amdgcn_cvt_f32_fp8(q[k], 0);
      float qy = __builtin_amdgcn_cvt_f32_fp8(q[k], 1);
      sx += qx; sy += qy;
      mxx = fmaxf(mxx, qx); mxy = fmaxf(mxy, qy);
    }
    i += 8;
  }
  if (i + 4 <= r1) {
    int s[4];
#pragma unroll
    for (int k = 0; k < 4; ++k) s[k] = __builtin_amdgcn_readfirstlane((int)csr_src[i + k]);
    u32 q[4];
#pragma unroll
    for (int k = 0; k < 4; ++k) q[k] = (u32)*(const u16*)(Qbase + (size_t)s[k] * 128);
#pragma unroll
    for (int k = 0; k < 4; ++k) {
      float qx = __builtin_amdgcn_cvt_f32_fp8(q[k], 0);
      float qy = __builtin_amdgcn_cvt_f32_fp8(q[k], 1);
      sx += qx; sy += qy;
      mxx = fmaxf(mxx, qx); mxy = fmaxf(mxy, qy);
    }
    i += 4;
  }
  for (; i < r1; ++i) {
    int s = __builtin_amdgcn_readfirstlane((int)csr_src[i]);
    u32 q = (u32)*(const u16*)(Qbase + (size_t)s * 128);
    float qx = __builtin_amdgcn_cvt_f32_fp8(q, 0);
    float qy = __builtin_amdgcn_cvt_f32_fp8(q, 1);
    sx += qx; sy += qy;
    mxx = fmaxf(mxx, qx); mxy = fmaxf(mxy, qy);
  }
  u32 pu = *(const u32*)(Pb + (size_t)wid * 128 + c);
  float2 b = *(const float2*)(pre_b + c);
  float px = bflo(pu) + b.x;
  float py = bfhi(pu) + b.y;
  int deg = r1 - r0;
  float vm_x = 0.f, vm_y = 0.f, vx_x = 0.f, vx_y = 0.f, vs_x = 0.f, vs_y = 0.f;
  if (deg > 0) {
    float inv = 1.0f / (float)deg;
    vm_x = px + sx * inv;          vm_y = py + sy * inv;
    vx_x = px + mxx;               vx_y = py + mxy;
    vs_x = (float)deg * px + sx;   vs_y = (float)deg * py + sy;
  }
  u16* arow = Xcat + (size_t)wid * 512 + 128;
  *(u32*)(arow + c)       = (u32)f2bf(vm_x) | ((u32)f2bf(vm_y) << 16);
  *(u32*)(arow + 128 + c) = (u32)f2bf(vx_x) | ((u32)f2bf(vx_y) << 16);
  *(u32*)(arow + 256 + c) = (u32)f2bf(vs_x) | ((u32)f2bf(vs_y) << 16);
}

extern "C" void kernel_launch(void* const* d_in, const int* in_sizes, int n_in,
                              void* d_out, int out_size, void* d_ws, size_t ws_size,
                              hipStream_t stream) {
  const float* x      = (const float*)d_in[0];
  const int*   ei     = (const int*)d_in[1];   // [0..E)=src, [E..2E)=dst
  const float* pre_W  = (const float*)d_in[2];
  const float* pre_b  = (const float*)d_in[3];
  const float* post_W = (const float*)d_in[4];
  const float* post_b = (const float*)d_in[5];
  const float* lin_W  = (const float*)d_in[6];
  const float* lin_b  = (const float*)d_in[7];
  float* out = (float*)d_out;

  char* ws = (char*)d_ws;
  size_t off = 0;
  auto alloc = [&](size_t bytes) { size_t o = off; off = (off + bytes + 511) & ~(size_t)511; return o; };
  u16*   Xcat    = (u16*)(ws + alloc((size_t)NN * 512 * 2));
  u16*   Pb      = (u16*)(ws + alloc((size_t)NN * 128 * 2));
  u8*    Qf8     = (u8*)(ws + alloc((size_t)NN * 128));
  u16*   WpT     = (u16*)(ws + alloc(128 * 512 * 2));
  u16*   WpqT    = (u16*)(ws + alloc(256 * 128 * 2));
  float* bp      = (float*)(ws + alloc(128 * 4));
  int*   row_ptr = (int*)(ws + alloc((size_t)(NN + 1) * 4));
  int*   bucket_part   = (int*)(ws + alloc((size_t)NB_CNT * 256 * 4));
  int*   bucket_base   = (int*)(ws + alloc(257 * 4));
  int*   bucket_cursor = (int*)(ws + alloc(256 * 4));
  u32*   ebuf    = (u32*)(ws + alloc((size_t)EE * 4));
  u16*   csr_src = (u16*)(ws + alloc((size_t)EE * 2));
  (void)ws_size; (void)in_sizes; (void)n_in; (void)out_size;

  const int NB_M = (NN + 127) / 128;       // 391

  k_setup<<<NB_SETUP, 256, 0, stream>>>(post_W, post_b, lin_W, lin_b, pre_W, ei,
                                        WpT, WpqT, bp, bucket_part);
  k_scanbucket<<<1, 256, 0, stream>>>(bucket_part, bucket_base, bucket_cursor);
  k_bucket<<<NB_CNT, 256, 0, stream>>>(ei, bucket_cursor, ebuf);
  k_sortbucket<<<NBKT, 256, 0, stream>>>(ebuf, bucket_base, row_ptr, csr_src);
  k_gemm_pq<<<NB_M, 512, 0, stream>>>(x, WpqT, Xcat, Pb, Qf8);
  k_aggr<<<(NN * 64 + 255) / 256, 256, 0, stream>>>(Pb, Qf8, pre_b, row_ptr, csr_src, Xcat);
  k_gemm_out<<<NB_M, 256, 0, stream>>>(Xcat, WpT, bp, out);
}